// Round 1
// baseline (3962.402 us; speedup 1.0000x reference)
//
#include <hip/hip_runtime.h>
#include <hip/hip_bf16.h>

typedef __hip_bfloat16 bf16;

#define DEVINL __device__ __forceinline__

constexpr int BATCH = 16384;
constexpr int DIN   = 1024;   // 2*E_DIM
constexpr int DHID  = 2048;   // 4*E_DIM
constexpr int NEXP  = 16;
constexpr int EXPSZ = 512;
constexpr int NPAIR = BATCH * 3;

// GEMM tile config
constexpr int BM = 128, BN = 128, BK = 16;

DEVINL float bf2f(unsigned short v) {
  union { unsigned int u; float f; } x; x.u = ((unsigned)v) << 16; return x.f;
}

// ---------------------------------------------------------------------------
// Generic fp32 tiled GEMM: C[M,N] = op(A[M,K] @ B[K,N] + bias)
// AMODE: 0 = fp32 A, linear rows
//        1 = concat(embP[row,512], embR[row,512]) as A row (K=1024)
//        2 = fp32 A, rows gathered via pairRow (expert mode)
//        3 = bf16 A, linear rows at pair offset (expert mode)
// EXPERT: blockIdx.z = expert; B/bias offset by expert; M = counts[e];
//         C rows written at pair index offs[e]+m.
// TASKB : B/bias offset by (*taskPtr) * K*N / N.
// SCALEW: multiply (acc+bias) by pairW[pair] (expert GEMM2 gate scaling).
// ---------------------------------------------------------------------------
template<int AMODE, bool EXPERT, bool TASKB, bool RELU, bool SCALEW, bool OUTBF>
__global__ __launch_bounds__(256, 2)
void gemm_k(const void* __restrict__ Av, const float* __restrict__ A2,
            const float* __restrict__ Bb, const float* __restrict__ biasb,
            void* __restrict__ Cv,
            const int* __restrict__ pairRow, const float* __restrict__ pairW,
            const int* __restrict__ counts, const int* __restrict__ offs,
            const int* __restrict__ taskPtr,
            int M, int N, int K)
{
  __shared__ float As[BK][BM];
  __shared__ float Bs[BK][BN];

  int Mloc = M;
  int rowBase = 0;
  const float* Bw = Bb;
  const float* bias = biasb;
  if (EXPERT) {
    const int e = blockIdx.z;
    Mloc = counts[e];
    rowBase = offs[e];
    Bw = Bb + (long)e * K * N;
    bias = biasb + (long)e * N;
  }
  if (TASKB) {
    const int t = *taskPtr;
    Bw = Bb + (long)t * K * N;
    bias = biasb + (long)t * N;
  }
  const int tile0 = blockIdx.x * BM;
  if (tile0 >= Mloc) return;
  const int col0 = blockIdx.y * BN;

  const int tid = threadIdx.x;
  const int am = tid >> 1;            // A-load row in tile
  const int ak = (tid & 1) * 8;       // A-load k offset
  const int bk = tid >> 4;            // B-load k
  const int bn = (tid & 15) * 8;      // B-load col
  const int rg = (tid >> 4) * 8;      // micro-tile row base
  const int cg = (tid & 15) * 8;      // micro-tile col base

  const bool arowValid = (tile0 + am) < Mloc;
  const float* aptr  = nullptr;
  const float* aptr2 = nullptr;
  const bf16*  aptrh = nullptr;
  if (AMODE == 0) {
    aptr = (const float*)Av + (long)(tile0 + am) * K;
  } else if (AMODE == 1) {
    aptr  = (const float*)Av + (long)(tile0 + am) * 512;
    aptr2 = A2              + (long)(tile0 + am) * 512;
  } else if (AMODE == 2) {
    const int p = rowBase + tile0 + am;
    const int r = arowValid ? pairRow[p] : 0;
    aptr = (const float*)Av + (long)r * K;
  } else {
    const int p = rowBase + tile0 + am;
    aptrh = (const bf16*)Av + (long)p * K;
  }

  float acc[8][8];
  #pragma unroll
  for (int i = 0; i < 8; ++i)
    #pragma unroll
    for (int j = 0; j < 8; ++j) acc[i][j] = 0.f;

  for (int kt = 0; kt < K; kt += BK) {
    float av[8];
    if (!arowValid) {
      #pragma unroll
      for (int i = 0; i < 8; ++i) av[i] = 0.f;
    } else if (AMODE == 3) {
      float4 r = *reinterpret_cast<const float4*>(aptrh + kt + ak);
      const unsigned short* us = reinterpret_cast<const unsigned short*>(&r);
      #pragma unroll
      for (int i = 0; i < 8; ++i) av[i] = bf2f(us[i]);
    } else if (AMODE == 1) {
      const int c = kt + ak;
      const float* src = (c < 512) ? (aptr + c) : (aptr2 + (c - 512));
      float4 x0 = *reinterpret_cast<const float4*>(src);
      float4 x1 = *reinterpret_cast<const float4*>(src + 4);
      av[0]=x0.x; av[1]=x0.y; av[2]=x0.z; av[3]=x0.w;
      av[4]=x1.x; av[5]=x1.y; av[6]=x1.z; av[7]=x1.w;
    } else {
      const float* src = aptr + kt + ak;
      float4 x0 = *reinterpret_cast<const float4*>(src);
      float4 x1 = *reinterpret_cast<const float4*>(src + 4);
      av[0]=x0.x; av[1]=x0.y; av[2]=x0.z; av[3]=x0.w;
      av[4]=x1.x; av[5]=x1.y; av[6]=x1.z; av[7]=x1.w;
    }
    #pragma unroll
    for (int i = 0; i < 8; ++i) As[ak + i][am] = av[i];

    {
      const float* bsrc = Bw + (long)(kt + bk) * N + (col0 + bn);
      float4 b0 = *reinterpret_cast<const float4*>(bsrc);
      float4 b1 = *reinterpret_cast<const float4*>(bsrc + 4);
      Bs[bk][bn+0]=b0.x; Bs[bk][bn+1]=b0.y; Bs[bk][bn+2]=b0.z; Bs[bk][bn+3]=b0.w;
      Bs[bk][bn+4]=b1.x; Bs[bk][bn+5]=b1.y; Bs[bk][bn+6]=b1.z; Bs[bk][bn+7]=b1.w;
    }
    __syncthreads();
    #pragma unroll
    for (int k = 0; k < BK; ++k) {
      float4 a0 = *reinterpret_cast<const float4*>(&As[k][rg]);
      float4 a1 = *reinterpret_cast<const float4*>(&As[k][rg + 4]);
      float4 c0 = *reinterpret_cast<const float4*>(&Bs[k][cg]);
      float4 c1 = *reinterpret_cast<const float4*>(&Bs[k][cg + 4]);
      const float a[8] = {a0.x,a0.y,a0.z,a0.w,a1.x,a1.y,a1.z,a1.w};
      const float b[8] = {c0.x,c0.y,c0.z,c0.w,c1.x,c1.y,c1.z,c1.w};
      #pragma unroll
      for (int i = 0; i < 8; ++i)
        #pragma unroll
        for (int j = 0; j < 8; ++j)
          acc[i][j] = fmaf(a[i], b[j], acc[i][j]);
    }
    __syncthreads();
  }

  #pragma unroll
  for (int i = 0; i < 8; ++i) {
    const int mr = tile0 + rg + i;
    if (mr >= Mloc) break;
    float w = 1.f;
    if (SCALEW) w = pairW[rowBase + mr];
    const long crow = EXPERT ? (long)(rowBase + mr) : (long)mr;
    #pragma unroll
    for (int j = 0; j < 8; ++j) {
      float v = acc[i][j] + bias[col0 + cg + j];
      if (RELU) v = fmaxf(v, 0.f);
      if (SCALEW) v *= w;
      if (OUTBF) ((bf16*)Cv)[crow * N + col0 + cg + j] = __float2bfloat16(v);
      else       ((float*)Cv)[crow * N + col0 + cg + j] = v;
    }
  }
}

// ---------------------------------------------------------------------------
// In-place LayerNorm (+ optional relu) over rows of COLS.
// ---------------------------------------------------------------------------
template<int COLS, bool RELU>
__global__ __launch_bounds__(256)
void ln_k(float* __restrict__ x, const float* __restrict__ g, const float* __restrict__ b)
{
  constexpr int PER = COLS / 256;
  const long row = blockIdx.x;
  float* xr = x + row * COLS;
  float v[PER];
  float s = 0.f, s2 = 0.f;
  #pragma unroll
  for (int i = 0; i < PER; ++i) {
    v[i] = xr[threadIdx.x + i * 256];
    s += v[i];
    s2 += v[i] * v[i];
  }
  #pragma unroll
  for (int o = 1; o < 64; o <<= 1) { s += __shfl_xor(s, o); s2 += __shfl_xor(s2, o); }
  __shared__ float ss[4], ss2[4];
  const int w = threadIdx.x >> 6;
  if ((threadIdx.x & 63) == 0) { ss[w] = s; ss2[w] = s2; }
  __syncthreads();
  s  = ss[0]  + ss[1]  + ss[2]  + ss[3];
  s2 = ss2[0] + ss2[1] + ss2[2] + ss2[3];
  const float mu  = s * (1.f / COLS);
  const float var = s2 * (1.f / COLS) - mu * mu;
  const float rs  = rsqrtf(var + 1e-5f);
  #pragma unroll
  for (int i = 0; i < PER; ++i) {
    const int c = threadIdx.x + i * 256;
    float y = (v[i] - mu) * rs * g[c] + b[c];
    if (RELU) y = fmaxf(y, 0.f);
    xr[c] = y;
  }
}

// ---------------------------------------------------------------------------
// logits = g @ gW2[t] + gb2[t]; top-3; softmax; write sparse gates; record
// topk and per-expert counts. One wave per row (4 rows / 256-thread block).
// ---------------------------------------------------------------------------
__global__ __launch_bounds__(256)
void gate_topk_k(const float* __restrict__ g, const float* __restrict__ gW2,
                 const float* __restrict__ gb2, const int* __restrict__ taskPtr,
                 float* __restrict__ gatesOut, int* __restrict__ topkIdx,
                 float* __restrict__ topkW, int* __restrict__ counts)
{
  const int t = *taskPtr;
  const float* W = gW2 + (long)t * 128 * 16;
  const float* bias = gb2 + (long)t * 16;
  const int lane = threadIdx.x & 63;
  const int row = blockIdx.x * 4 + (threadIdx.x >> 6);
  const float* gr = g + (long)row * 128;
  const int e = lane & 15;
  const int q = lane >> 4;
  float s = 0.f;
  for (int j = q * 32; j < q * 32 + 32; ++j) s = fmaf(gr[j], W[j * 16 + e], s);
  s += __shfl_xor(s, 16);
  s += __shfl_xor(s, 32);
  s += bias[e];
  float logits[16];
  #pragma unroll
  for (int i = 0; i < 16; ++i) logits[i] = __shfl(s, i);
  int i0 = 0; float v0 = logits[0];
  #pragma unroll
  for (int i = 1; i < 16; ++i) if (logits[i] > v0) { v0 = logits[i]; i0 = i; }
  int i1 = -1; float v1 = -3.4e38f;
  #pragma unroll
  for (int i = 0; i < 16; ++i) if (i != i0 && logits[i] > v1) { v1 = logits[i]; i1 = i; }
  int i2 = -1; float v2 = -3.4e38f;
  #pragma unroll
  for (int i = 0; i < 16; ++i) if (i != i0 && i != i1 && logits[i] > v2) { v2 = logits[i]; i2 = i; }
  const float ex1 = expf(v1 - v0);
  const float ex2 = expf(v2 - v0);
  const float inv = 1.f / (1.f + ex1 + ex2);
  const float p0 = inv, p1 = ex1 * inv, p2 = ex2 * inv;
  if (lane < 16) {
    const float gv = (lane == i0) ? p0 : (lane == i1) ? p1 : (lane == i2) ? p2 : 0.f;
    gatesOut[(long)row * 16 + lane] = gv;
  }
  if (lane == 0) {
    topkIdx[row * 3 + 0] = i0; topkIdx[row * 3 + 1] = i1; topkIdx[row * 3 + 2] = i2;
    topkW [row * 3 + 0] = p0; topkW [row * 3 + 1] = p1; topkW [row * 3 + 2] = p2;
    atomicAdd(&counts[i0], 1);
    atomicAdd(&counts[i1], 1);
    atomicAdd(&counts[i2], 1);
  }
}

__global__ void scan_k(const int* __restrict__ counts, int* __restrict__ offs,
                       int* __restrict__ cursor)
{
  if (threadIdx.x == 0) {
    int a = 0;
    for (int e = 0; e < NEXP; ++e) { offs[e] = a; cursor[e] = a; a += counts[e]; }
  }
}

__global__ __launch_bounds__(256)
void fill_k(const int* __restrict__ topkIdx, const float* __restrict__ topkW,
            int* __restrict__ cursor, int* __restrict__ pairRow,
            float* __restrict__ pairW, int* __restrict__ rowPos)
{
  const int row = blockIdx.x * 256 + threadIdx.x;
  #pragma unroll
  for (int k = 0; k < 3; ++k) {
    const int ex = topkIdx[row * 3 + k];
    const int pos = atomicAdd(&cursor[ex], 1);
    pairRow[pos] = row;
    pairW[pos] = topkW[row * 3 + k];
    rowPos[row * 3 + k] = pos;
  }
}

// mix[row] = sum over the row's 3 pair slots (fixed k order -> deterministic)
__global__ __launch_bounds__(256)
void mixreduce_k(const bf16* __restrict__ eo, const int* __restrict__ rowPos,
                 float* __restrict__ mix)
{
  const long row = blockIdx.x;
  const long p0 = rowPos[row * 3 + 0];
  const long p1 = rowPos[row * 3 + 1];
  const long p2 = rowPos[row * 3 + 2];
  for (int c = threadIdx.x; c < EXPSZ; c += 256) {
    const float v = __bfloat162float(eo[p0 * EXPSZ + c])
                  + __bfloat162float(eo[p1 * EXPSZ + c])
                  + __bfloat162float(eo[p2 * EXPSZ + c]);
    mix[row * EXPSZ + c] = v;
  }
}

__global__ __launch_bounds__(256)
void tower3_k(const float* __restrict__ t2, const float* __restrict__ tW3,
              const float* __restrict__ tb3, const int* __restrict__ taskPtr,
              float* __restrict__ out)
{
  const int t = *taskPtr;
  const float* w = tW3 + (long)t * 128;
  const float bias = tb3[t];
  const int lane = threadIdx.x & 63;
  const int row = blockIdx.x * 4 + (threadIdx.x >> 6);
  const float* x = t2 + (long)row * 128;
  float s = fmaf(x[lane], w[lane], x[lane + 64] * w[lane + 64]);
  #pragma unroll
  for (int o = 1; o < 64; o <<= 1) s += __shfl_xor(s, o);
  if (lane == 0) out[row] = 1.f / (1.f + expf(-s + (-bias) * 0.f - bias * 0.f - 0.f) ) * 0.f + 1.f / (1.f + expf(-(s + bias)));
  if (blockIdx.x == 0 && threadIdx.x == 0) out[BATCH] = (float)t;
}

// ---------------------------------------------------------------------------
extern "C" void kernel_launch(void* const* d_in, const int* in_sizes, int n_in,
                              void* d_out, int out_size, void* d_ws, size_t ws_size,
                              hipStream_t stream)
{
  const float* embP  = (const float*)d_in[0];
  const float* embR  = (const float*)d_in[1];
  const float* encW1 = (const float*)d_in[2];
  const float* encB1 = (const float*)d_in[3];
  const float* ln1g  = (const float*)d_in[4];
  const float* ln1b  = (const float*)d_in[5];
  const float* encW2 = (const float*)d_in[6];
  const float* encB2 = (const float*)d_in[7];
  const float* ln2g  = (const float*)d_in[8];
  const float* ln2b  = (const float*)d_in[9];
  const float* gW1   = (const float*)d_in[10];
  const float* gb1   = (const float*)d_in[11];
  const float* gW2   = (const float*)d_in[12];
  const float* gb2   = (const float*)d_in[13];
  const float* We1   = (const float*)d_in[14];
  const float* be1   = (const float*)d_in[15];
  const float* We2   = (const float*)d_in[16];
  const float* be2   = (const float*)d_in[17];
  const float* tW1   = (const float*)d_in[18];
  const float* tb1   = (const float*)d_in[19];
  const float* tW2   = (const float*)d_in[20];
  const float* tb2   = (const float*)d_in[21];
  const float* tW3   = (const float*)d_in[22];
  const float* tb3   = (const float*)d_in[23];
  const int* taskPtr = (const int*)d_in[24];

  float* out = (float*)d_out;
  char* ws = (char*)d_ws;

  // ws layout (aliased by lifetime):
  //  [0, 128MB)      : h fp32 [16384,2048]   -> later e1 bf16 [49152,512] + eo bf16 [49152,512]
  //  [128MB, 192MB)  : feat fp32 [16384,1024]-> later mix fp32 + t1 + t2
  //  [192MB, 200MB)  : g fp32 [16384,128]
  //  [200MB, ~201MB) : dispatch metadata
  float* h    = (float*)(ws);
  bf16*  e1b  = (bf16*)(ws);
  bf16*  eob  = (bf16*)(ws + 50331648);
  float* feat = (float*)(ws + 134217728);
  float* mix  = (float*)(ws + 134217728);
  float* t1   = (float*)(ws + 134217728 + 33554432);
  float* t2v  = (float*)(ws + 134217728 + 50331648);
  float* gbuf = (float*)(ws + 201326592);
  char* small  = ws + 209715200;
  int*   counts  = (int*)  (small);
  int*   offs    = (int*)  (small + 256);
  int*   cursor  = (int*)  (small + 512);
  int*   topkIdx = (int*)  (small + 1024);
  float* topkW   = (float*)(small + 1024 + 196608);
  int*   pairRow = (int*)  (small + 1024 + 2 * 196608);
  float* pairW   = (float*)(small + 1024 + 3 * 196608);
  int*   rowPos  = (int*)  (small + 1024 + 4 * 196608);

  hipMemsetAsync(counts, 0, 256, stream);

  const dim3 blk(256, 1, 1);

  // h = concat(embP, embR) @ enc_W1 + b1
  gemm_k<1,false,false,false,false,false><<<dim3(BATCH/BM, DHID/BN, 1), blk, 0, stream>>>(
      embP, embR, encW1, encB1, h, nullptr, nullptr, nullptr, nullptr, nullptr, BATCH, DHID, DIN);
  // h = relu(LN(h))
  ln_k<DHID, true><<<dim3(BATCH, 1, 1), blk, 0, stream>>>(h, ln1g, ln1b);
  // feat_pre = h @ enc_W2 + b2
  gemm_k<0,false,false,false,false,false><<<dim3(BATCH/BM, DIN/BN, 1), blk, 0, stream>>>(
      h, nullptr, encW2, encB2, feat, nullptr, nullptr, nullptr, nullptr, nullptr, BATCH, DIN, DHID);
  // feat = LN(feat_pre)
  ln_k<DIN, false><<<dim3(BATCH, 1, 1), blk, 0, stream>>>(feat, ln2g, ln2b);
  // g = relu(feat @ gW1[t] + gb1[t])
  gemm_k<0,false,true,true,false,false><<<dim3(BATCH/BM, 1, 1), blk, 0, stream>>>(
      feat, nullptr, gW1, gb1, gbuf, nullptr, nullptr, nullptr, nullptr, taskPtr, BATCH, 128, DIN);
  // logits, top-3, softmax -> gates (d_out) + dispatch metadata
  gate_topk_k<<<dim3(BATCH/4, 1, 1), blk, 0, stream>>>(
      gbuf, gW2, gb2, taskPtr, out + BATCH + 1, topkIdx, topkW, counts);
  scan_k<<<dim3(1,1,1), dim3(64,1,1), 0, stream>>>(counts, offs, cursor);
  fill_k<<<dim3(BATCH/256, 1, 1), blk, 0, stream>>>(topkIdx, topkW, cursor, pairRow, pairW, rowPos);
  // e1[p] = relu(feat[pairRow[p]] @ We1[e] + be1[e])   (grouped, gathered)
  gemm_k<2,true,false,true,false,true><<<dim3(BATCH/BM, EXPSZ/BN, NEXP), blk, 0, stream>>>(
      feat, nullptr, We1, be1, e1b, pairRow, nullptr, counts, offs, nullptr, BATCH, EXPSZ, DIN);
  // eo[p] = w_p * (e1[p] @ We2[e] + be2[e])
  gemm_k<3,true,false,false,true,true><<<dim3(BATCH/BM, EXPSZ/BN, NEXP), blk, 0, stream>>>(
      e1b, nullptr, We2, be2, eob, nullptr, pairW, counts, offs, nullptr, BATCH, EXPSZ, EXPSZ);
  // mix[row] = sum of its 3 eo slots
  mixreduce_k<<<dim3(BATCH, 1, 1), blk, 0, stream>>>(eob, rowPos, mix);
  // towers
  gemm_k<0,false,true,true,false,false><<<dim3(BATCH/BM, 256/BN, 1), blk, 0, stream>>>(
      mix, nullptr, tW1, tb1, t1, nullptr, nullptr, nullptr, nullptr, taskPtr, BATCH, 256, EXPSZ);
  gemm_k<0,false,true,true,false,false><<<dim3(BATCH/BM, 1, 1), blk, 0, stream>>>(
      t1, nullptr, tW2, tb2, t2v, nullptr, nullptr, nullptr, nullptr, taskPtr, BATCH, 128, 256);
  tower3_k<<<dim3(BATCH/4, 1, 1), blk, 0, stream>>>(t2v, tW3, tb3, taskPtr, out);
}

// Round 4
// 2753.979 us; speedup vs baseline: 1.4388x; 1.4388x over previous
//
#include <hip/hip_runtime.h>

typedef __attribute__((ext_vector_type(8))) short bf16x8;
typedef __attribute__((ext_vector_type(4))) float f32x4;

#define DEVINL __device__ __forceinline__

constexpr int BATCH = 16384;
constexpr int DIN   = 1024;
constexpr int DHID  = 2048;
constexpr int NEXP  = 16;
constexpr int EXPSZ = 512;
constexpr int NPAIR = BATCH * 3;

DEVINL float bf2f(unsigned short v) {
  union { unsigned u; float f; } x; x.u = ((unsigned)v) << 16; return x.f;
}
DEVINL unsigned short f2bfbits(float f) {   // round-to-nearest-even bf16
  union { float f; unsigned u; } x; x.f = f;
  unsigned r = x.u + 0x7fff + ((x.u >> 16) & 1);
  return (unsigned short)(r >> 16);
}

DEVINL void gl2lds(const unsigned short* src, char* ldst) {
  __builtin_amdgcn_global_load_lds((const __attribute__((address_space(1))) void*)src,
                                   (__attribute__((address_space(3))) void*)ldst, 16, 0, 0);
}

// ---------------------------------------------------------------------------
// Split-bf16 MFMA GEMM, 128x128 tile, 4 waves (2x2 of 64x64), 16x16x32 bf16.
// A source is fp32 (reg-staged, split in-register into ALEV bf16 levels) or
// bf16 (global_load_lds). B pre-split into BLEV bf16 arrays Bt[N][K] (per
// expert when AMODE 1/2). Terms a_i x b_j with i+j <= LMAX are accumulated
// (smallest first). LDS fragment-contiguous: unit u (16B) = g*128 + row,
// holding elems [row][kt + g*8 .. +7].
// AMODE: 0 = linear fp32 rows      (encoder GEMM2)
//        1 = gather fp32 rows via pairRow (expert GEMM1)
//        2 = pair-linear bf16 rows (expert GEMM2)
//        3 = concat(embP,embR) fp32 (encoder GEMM1; Av=embP, Av2=embR)
// EPI:   0 = +bias -> fp32 Cf
//        1 = +bias, relu -> bf16 Cb
//        2 = +bias, *pairW -> bf16 Cb
// ---------------------------------------------------------------------------
template<int ALEV, int BLEV, int LMAX, int AMODE, int EPI, int BK>
__global__ __launch_bounds__(256, 2)
void mgemm_k(const void* __restrict__ Av, const void* __restrict__ Av2,
             const unsigned short* __restrict__ B0p,
             const unsigned short* __restrict__ B1p,
             const unsigned short* __restrict__ B2p,
             const float* __restrict__ biasb,
             float* __restrict__ Cf, unsigned short* __restrict__ Cb,
             const int* __restrict__ pairRow, const float* __restrict__ pairW,
             const int* __restrict__ counts, const int* __restrict__ offs,
             int M, int N, int K)
{
  constexpr int KG = BK / 8;
  constexpr int UNITS = 128 * KG;
  constexpr int ISS = UNITS / 256;
  constexpr bool AFP32 = (AMODE != 2);
  constexpr bool EXPERT = (AMODE == 1 || AMODE == 2);
  __shared__ char smem[(ALEV + BLEV) * UNITS * 16];
  char* sA0 = smem;
  char* sA1 = smem + UNITS * 16;
  char* sA2 = smem + 2 * UNITS * 16;
  char* sB0 = smem + ALEV * UNITS * 16;
  char* sB1 = smem + (ALEV + 1) * UNITS * 16;
  char* sB2 = smem + (ALEV + 2) * UNITS * 16;

  int Mloc = M, rowBase = 0;
  const unsigned short* b0 = B0p;
  const unsigned short* b1 = B1p;
  const unsigned short* b2 = B2p;
  const float* bias = biasb;
  if (EXPERT) {
    const int e = blockIdx.z;
    Mloc = counts[e];
    rowBase = offs[e];
    const size_t eo = (size_t)e * (size_t)K * N;
    b0 = B0p + eo;
    if (BLEV > 1) b1 = B1p + eo;
    if (BLEV > 2) b2 = B2p + eo;
    bias = biasb + (size_t)e * N;
  }
  const int tile0 = blockIdx.x * 128;
  if (tile0 >= Mloc) return;
  const int col0 = blockIdx.y * 128;
  const int tid = threadIdx.x;
  const int lane = tid & 63;
  const int wr = ((tid >> 6) >> 1) * 64;
  const int wc = ((tid >> 6) & 1) * 64;

  // per-thread staging row (fixed across K)
  const int srow = tid & 127;
  const float* aP = nullptr;           // concat halves (AMODE 3)
  const float* aR = nullptr;
  const float* aF = nullptr;           // fp32 row (AMODE 0/1)
  const unsigned short* aB = nullptr;  // bf16 row (AMODE 2)
  if (AMODE == 3) {
    aP = (const float*)Av  + (size_t)(tile0 + srow) * 512;
    aR = (const float*)Av2 + (size_t)(tile0 + srow) * 512;
  } else if (AMODE == 0) {
    aF = (const float*)Av + (size_t)(tile0 + srow) * K;
  } else if (AMODE == 1) {
    int p = rowBase + tile0 + srow; p = p < NPAIR - 1 ? p : NPAIR - 1;
    aF = (const float*)Av + (size_t)pairRow[p] * K;
  } else {
    int p = rowBase + tile0 + srow; p = p < NPAIR - 1 ? p : NPAIR - 1;
    aB = (const unsigned short*)Av + (size_t)p * K;
  }
  const size_t boff = (size_t)(col0 + srow) * K;

  f32x4 acc[4][4];
  #pragma unroll
  for (int m = 0; m < 4; ++m)
    #pragma unroll
    for (int n = 0; n < 4; ++n) acc[m][n] = f32x4{0.f, 0.f, 0.f, 0.f};

  for (int kt = 0; kt < K; kt += BK) {
    if (AFP32) {
      // reg-stage A: load fp32, split to ALEV bf16 levels, ds_write
      #pragma unroll
      for (int it = 0; it < ISS; ++it) {
        const int u = it * 256 + tid;
        const int ko = kt + (u >> 7) * 8;
        const float* s;
        if (AMODE == 3) s = (ko < 512) ? (aP + ko) : (aR + (ko - 512));
        else            s = aF + ko;
        const float4 x0 = *(const float4*)s;
        const float4 x1 = *(const float4*)(s + 4);
        const float vv[8] = {x0.x, x0.y, x0.z, x0.w, x1.x, x1.y, x1.z, x1.w};
        bf16x8 q0, q1, q2;
        #pragma unroll
        for (int j = 0; j < 8; ++j) {
          const unsigned short c0 = f2bfbits(vv[j]);
          q0[j] = (short)c0;
          if (ALEV > 1) {
            const float r1v = vv[j] - bf2f(c0);
            const unsigned short c1 = f2bfbits(r1v);
            q1[j] = (short)c1;
            if (ALEV > 2) q2[j] = (short)f2bfbits(r1v - bf2f(c1));
          }
        }
        *(bf16x8*)(sA0 + (size_t)u * 16) = q0;
        if (ALEV > 1) *(bf16x8*)(sA1 + (size_t)u * 16) = q1;
        if (ALEV > 2) *(bf16x8*)(sA2 + (size_t)u * 16) = q2;
      }
    }
    #pragma unroll
    for (int it = 0; it < ISS; ++it) {
      const int g = it * 2 + (tid >> 7);
      const int uo = (it * 256 + (tid & 192)) * 16;   // wave-uniform LDS base
      const int ko = kt + g * 8;
      if (!AFP32) gl2lds(aB + ko, sA0 + uo);
      gl2lds(b0 + boff + ko, sB0 + uo);
      if (BLEV > 1) gl2lds(b1 + boff + ko, sB1 + uo);
      if (BLEV > 2) gl2lds(b2 + boff + ko, sB2 + uo);
    }
    __syncthreads();
    #pragma unroll
    for (int kk = 0; kk < BK / 32; ++kk) {
      const int g = kk * 4 + (lane >> 4);
      bf16x8 b0f[4], b1f[4], b2f[4];
      #pragma unroll
      for (int n = 0; n < 4; ++n) {
        const size_t off = (size_t)(g * 128 + wc + n * 16 + (lane & 15)) * 16;
        b0f[n] = *(const bf16x8*)(sB0 + off);
        if (BLEV > 1) b1f[n] = *(const bf16x8*)(sB1 + off);
        if (BLEV > 2) b2f[n] = *(const bf16x8*)(sB2 + off);
      }
      #pragma unroll
      for (int m = 0; m < 4; ++m) {
        const size_t aoff = (size_t)(g * 128 + wr + m * 16 + (lane & 15)) * 16;
        const bf16x8 a0 = *(const bf16x8*)(sA0 + aoff);
        bf16x8 a1, a2;
        if (ALEV > 1) a1 = *(const bf16x8*)(sA1 + aoff);
        if (ALEV > 2) a2 = *(const bf16x8*)(sA2 + aoff);
        #pragma unroll
        for (int n = 0; n < 4; ++n) {
          // smallest-magnitude terms first
          if (ALEV > 2 && LMAX >= 2)
            acc[m][n] = __builtin_amdgcn_mfma_f32_16x16x32_bf16(a2, b0f[n], acc[m][n], 0, 0, 0);
          if (ALEV > 1 && BLEV > 1 && LMAX >= 2)
            acc[m][n] = __builtin_amdgcn_mfma_f32_16x16x32_bf16(a1, b1f[n], acc[m][n], 0, 0, 0);
          if (BLEV > 2 && LMAX >= 2)
            acc[m][n] = __builtin_amdgcn_mfma_f32_16x16x32_bf16(a0, b2f[n], acc[m][n], 0, 0, 0);
          if (ALEV > 1 && LMAX >= 1)
            acc[m][n] = __builtin_amdgcn_mfma_f32_16x16x32_bf16(a1, b0f[n], acc[m][n], 0, 0, 0);
          if (BLEV > 1 && LMAX >= 1)
            acc[m][n] = __builtin_amdgcn_mfma_f32_16x16x32_bf16(a0, b1f[n], acc[m][n], 0, 0, 0);
          acc[m][n] = __builtin_amdgcn_mfma_f32_16x16x32_bf16(a0, b0f[n], acc[m][n], 0, 0, 0);
        }
      }
    }
    __syncthreads();
  }

  // epilogue. C/D mapping: col = lane&15, row = (lane>>4)*4 + j  [m89-verified]
  #pragma unroll
  for (int n = 0; n < 4; ++n) {
    const int cn = col0 + wc + n * 16 + (lane & 15);
    const float bv = bias[cn];
    #pragma unroll
    for (int m = 0; m < 4; ++m) {
      const int r0 = wr + m * 16 + ((lane >> 4) << 2);
      #pragma unroll
      for (int j = 0; j < 4; ++j) {
        const int rm = tile0 + r0 + j;
        if (EXPERT && rm >= Mloc) continue;
        const float v = acc[m][n][j] + bv;
        const size_t ci = (size_t)(EXPERT ? (rowBase + rm) : rm) * N + cn;
        if (EPI == 0) {
          Cf[ci] = v;
        } else if (EPI == 1) {
          Cb[ci] = f2bfbits(fmaxf(v, 0.f));
        } else {
          Cb[ci] = f2bfbits(v * pairW[rowBase + rm]);
        }
      }
    }
  }
}

// ---------------------------------------------------------------------------
// fp32 vector GEMM (gate + towers) — round-1 verbatim path.
// C = relu(A@B[t] + bias[t]), fp32.
// ---------------------------------------------------------------------------
template<bool RELU>
__global__ __launch_bounds__(256, 2)
void gemm32_k(const float* __restrict__ Av, const float* __restrict__ Bb,
              const float* __restrict__ biasb, float* __restrict__ Cv,
              const int* __restrict__ taskPtr, int M, int N, int K)
{
  __shared__ float As[16][128];
  __shared__ float Bs[16][128];
  const int t = *taskPtr;
  const float* Bw = Bb + (size_t)t * K * N;
  const float* bias = biasb + (size_t)t * N;
  const int tile0 = blockIdx.x * 128;
  const int col0 = blockIdx.y * 128;
  const int tid = threadIdx.x;
  const int am = tid >> 1, ak = (tid & 1) * 8;
  const int bk = tid >> 4, bn = (tid & 15) * 8;
  const int rg = (tid >> 4) * 8, cg = (tid & 15) * 8;
  const float* aptr = Av + (size_t)(tile0 + am) * K;

  float acc[8][8];
  #pragma unroll
  for (int i = 0; i < 8; ++i)
    #pragma unroll
    for (int j = 0; j < 8; ++j) acc[i][j] = 0.f;

  for (int kt = 0; kt < K; kt += 16) {
    {
      const float* src = aptr + kt + ak;
      float4 x0 = *reinterpret_cast<const float4*>(src);
      float4 x1 = *reinterpret_cast<const float4*>(src + 4);
      As[ak+0][am]=x0.x; As[ak+1][am]=x0.y; As[ak+2][am]=x0.z; As[ak+3][am]=x0.w;
      As[ak+4][am]=x1.x; As[ak+5][am]=x1.y; As[ak+6][am]=x1.z; As[ak+7][am]=x1.w;
    }
    {
      const float* bsrc = Bw + (size_t)(kt + bk) * N + (col0 + bn);
      float4 b0 = *reinterpret_cast<const float4*>(bsrc);
      float4 b1 = *reinterpret_cast<const float4*>(bsrc + 4);
      Bs[bk][bn+0]=b0.x; Bs[bk][bn+1]=b0.y; Bs[bk][bn+2]=b0.z; Bs[bk][bn+3]=b0.w;
      Bs[bk][bn+4]=b1.x; Bs[bk][bn+5]=b1.y; Bs[bk][bn+6]=b1.z; Bs[bk][bn+7]=b1.w;
    }
    __syncthreads();
    #pragma unroll
    for (int k = 0; k < 16; ++k) {
      float4 a0 = *reinterpret_cast<const float4*>(&As[k][rg]);
      float4 a1 = *reinterpret_cast<const float4*>(&As[k][rg + 4]);
      float4 c0 = *reinterpret_cast<const float4*>(&Bs[k][cg]);
      float4 c1 = *reinterpret_cast<const float4*>(&Bs[k][cg + 4]);
      const float a[8] = {a0.x,a0.y,a0.z,a0.w,a1.x,a1.y,a1.z,a1.w};
      const float b[8] = {c0.x,c0.y,c0.z,c0.w,c1.x,c1.y,c1.z,c1.w};
      #pragma unroll
      for (int i = 0; i < 8; ++i)
        #pragma unroll
        for (int j = 0; j < 8; ++j)
          acc[i][j] = fmaf(a[i], b[j], acc[i][j]);
    }
    __syncthreads();
  }
  #pragma unroll
  for (int i = 0; i < 8; ++i) {
    const int mr = tile0 + rg + i;
    #pragma unroll
    for (int j = 0; j < 8; ++j) {
      float v = acc[i][j] + bias[col0 + cg + j];
      if (RELU) v = fmaxf(v, 0.f);
      Cv[(size_t)mr * N + col0 + cg + j] = v;
    }
  }
}

// ---------------------------------------------------------------------------
// transpose+convert: src fp32 [z][R][C] -> LEV bf16 split levels, [z][C][R]
// ---------------------------------------------------------------------------
template<int LEV>
__global__ __launch_bounds__(256)
void transp_k(const float* __restrict__ src, unsigned short* __restrict__ d0,
              unsigned short* __restrict__ d1, unsigned short* __restrict__ d2,
              int R, int C)
{
  __shared__ float tle[32][33];
  const size_t bb = (size_t)blockIdx.z * R * C;
  const int r0 = blockIdx.x * 32, c0 = blockIdx.y * 32;
  const int x = threadIdx.x & 31, y = threadIdx.x >> 5;
  #pragma unroll
  for (int i = 0; i < 32; i += 8)
    tle[y + i][x] = src[bb + (size_t)(r0 + y + i) * C + (c0 + x)];
  __syncthreads();
  #pragma unroll
  for (int i = 0; i < 32; i += 8) {
    const float v = tle[x][y + i];
    const size_t di = bb + (size_t)(c0 + y + i) * R + (r0 + x);
    const unsigned short b0 = f2bfbits(v);
    d0[di] = b0;
    if (LEV > 1) {
      const float r1 = v - bf2f(b0);
      const unsigned short b1 = f2bfbits(r1);
      d1[di] = b1;
      if (LEV > 2) d2[di] = f2bfbits(r1 - bf2f(b1));
    }
  }
}

// ---------------------------------------------------------------------------
// In-place LayerNorm (+ optional relu) over fp32 rows of COLS (round-1).
// ---------------------------------------------------------------------------
template<int COLS, bool RELU>
__global__ __launch_bounds__(256)
void ln_k(float* __restrict__ x, const float* __restrict__ g, const float* __restrict__ b)
{
  constexpr int PER = COLS / 256;
  const size_t row = blockIdx.x;
  float* xr = x + row * COLS;
  float v[PER];
  float s = 0.f, s2 = 0.f;
  #pragma unroll
  for (int i = 0; i < PER; ++i) {
    v[i] = xr[threadIdx.x + i * 256];
    s += v[i];
    s2 += v[i] * v[i];
  }
  #pragma unroll
  for (int o = 1; o < 64; o <<= 1) { s += __shfl_xor(s, o); s2 += __shfl_xor(s2, o); }
  __shared__ float ss[4], ss2[4];
  const int w = threadIdx.x >> 6;
  if ((threadIdx.x & 63) == 0) { ss[w] = s; ss2[w] = s2; }
  __syncthreads();
  s  = ss[0] + ss[1] + ss[2] + ss[3];
  s2 = ss2[0] + ss2[1] + ss2[2] + ss2[3];
  const float mu = s * (1.f / COLS);
  const float var = s2 * (1.f / COLS) - mu * mu;
  const float rs = rsqrtf(var + 1e-5f);
  #pragma unroll
  for (int i = 0; i < PER; ++i) {
    const int c = threadIdx.x + i * 256;
    float y = (v[i] - mu) * rs * g[c] + b[c];
    if (RELU) y = fmaxf(y, 0.f);
    xr[c] = y;
  }
}

// ---------------------------------------------------------------------------
__global__ __launch_bounds__(256)
void gate_topk_k(const float* __restrict__ g, const float* __restrict__ gW2,
                 const float* __restrict__ gb2, const int* __restrict__ taskPtr,
                 float* __restrict__ gatesOut, int* __restrict__ topkIdx,
                 float* __restrict__ topkW, int* __restrict__ counts)
{
  const int t = *taskPtr;
  const float* W = gW2 + (size_t)t * 128 * 16;
  const float* bias = gb2 + (size_t)t * 16;
  const int lane = threadIdx.x & 63;
  const int row = blockIdx.x * 4 + (threadIdx.x >> 6);
  const float* gr = g + (size_t)row * 128;
  const int e = lane & 15;
  const int q = lane >> 4;
  float s = 0.f;
  for (int j = q * 32; j < q * 32 + 32; ++j) s = fmaf(gr[j], W[j * 16 + e], s);
  s += __shfl_xor(s, 16);
  s += __shfl_xor(s, 32);
  s += bias[e];
  float logits[16];
  #pragma unroll
  for (int i = 0; i < 16; ++i) logits[i] = __shfl(s, i);
  int i0 = 0; float v0 = logits[0];
  #pragma unroll
  for (int i = 1; i < 16; ++i) if (logits[i] > v0) { v0 = logits[i]; i0 = i; }
  int i1 = -1; float v1 = -3.4e38f;
  #pragma unroll
  for (int i = 0; i < 16; ++i) if (i != i0 && logits[i] > v1) { v1 = logits[i]; i1 = i; }
  int i2 = -1; float v2 = -3.4e38f;
  #pragma unroll
  for (int i = 0; i < 16; ++i) if (i != i0 && i != i1 && logits[i] > v2) { v2 = logits[i]; i2 = i; }
  const float ex1 = expf(v1 - v0);
  const float ex2 = expf(v2 - v0);
  const float inv = 1.f / (1.f + ex1 + ex2);
  const float p0 = inv, p1 = ex1 * inv, p2 = ex2 * inv;
  if (lane < 16) {
    const float gv = (lane == i0) ? p0 : (lane == i1) ? p1 : (lane == i2) ? p2 : 0.f;
    gatesOut[(size_t)row * 16 + lane] = gv;
  }
  if (lane == 0) {
    topkIdx[row * 3 + 0] = i0; topkIdx[row * 3 + 1] = i1; topkIdx[row * 3 + 2] = i2;
    topkW [row * 3 + 0] = p0; topkW [row * 3 + 1] = p1; topkW [row * 3 + 2] = p2;
    atomicAdd(&counts[i0], 1);
    atomicAdd(&counts[i1], 1);
    atomicAdd(&counts[i2], 1);
  }
}

__global__ void scan_k(const int* __restrict__ counts, int* __restrict__ offs,
                       int* __restrict__ cursor)
{
  if (threadIdx.x == 0) {
    int a = 0;
    for (int e = 0; e < NEXP; ++e) { offs[e] = a; cursor[e] = a; a += counts[e]; }
  }
}

__global__ __launch_bounds__(256)
void fill_k(const int* __restrict__ topkIdx, const float* __restrict__ topkW,
            int* __restrict__ cursor, int* __restrict__ pairRow,
            float* __restrict__ pairW, int* __restrict__ rowPos)
{
  const int row = blockIdx.x * 256 + threadIdx.x;
  #pragma unroll
  for (int k = 0; k < 3; ++k) {
    const int ex = topkIdx[row * 3 + k];
    const int pos = atomicAdd(&cursor[ex], 1);
    pairRow[pos] = row;
    pairW[pos] = topkW[row * 3 + k];
    rowPos[row * 3 + k] = pos;
  }
}

__global__ __launch_bounds__(256)
void mixreduce_k(const unsigned short* __restrict__ eo, const int* __restrict__ rowPos,
                 float* __restrict__ mix)
{
  const size_t row = blockIdx.x;
  const size_t p0 = rowPos[row * 3 + 0];
  const size_t p1 = rowPos[row * 3 + 1];
  const size_t p2 = rowPos[row * 3 + 2];
  for (int c = threadIdx.x; c < EXPSZ; c += 256) {
    mix[row * EXPSZ + c] = bf2f(eo[p0 * EXPSZ + c]) + bf2f(eo[p1 * EXPSZ + c])
                         + bf2f(eo[p2 * EXPSZ + c]);
  }
}

__global__ __launch_bounds__(256)
void tower3_k(const float* __restrict__ t2, const float* __restrict__ tW3,
              const float* __restrict__ tb3, const int* __restrict__ taskPtr,
              float* __restrict__ out)
{
  const int t = *taskPtr;
  const float* w = tW3 + (size_t)t * 128;
  const float bias = tb3[t];
  const int lane = threadIdx.x & 63;
  const int row = blockIdx.x * 4 + (threadIdx.x >> 6);
  const float* x = t2 + (size_t)row * 128;
  float s = fmaf(x[lane], w[lane], x[lane + 64] * w[lane + 64]);
  #pragma unroll
  for (int o = 1; o < 64; o <<= 1) s += __shfl_xor(s, o);
  if (lane == 0) out[row] = 1.f / (1.f + expf(-(s + bias)));
  if (blockIdx.x == 0 && threadIdx.x == 0) out[BATCH] = (float)t;
}

// ---------------------------------------------------------------------------
extern "C" void kernel_launch(void* const* d_in, const int* in_sizes, int n_in,
                              void* d_out, int out_size, void* d_ws, size_t ws_size,
                              hipStream_t stream)
{
  (void)in_sizes; (void)n_in; (void)out_size; (void)ws_size;
  const float* embP  = (const float*)d_in[0];
  const float* embR  = (const float*)d_in[1];
  const float* encW1 = (const float*)d_in[2];
  const float* encB1 = (const float*)d_in[3];
  const float* ln1g  = (const float*)d_in[4];
  const float* ln1b  = (const float*)d_in[5];
  const float* encW2 = (const float*)d_in[6];
  const float* encB2 = (const float*)d_in[7];
  const float* ln2g  = (const float*)d_in[8];
  const float* ln2b  = (const float*)d_in[9];
  const float* gW1   = (const float*)d_in[10];
  const float* gb1   = (const float*)d_in[11];
  const float* gW2   = (const float*)d_in[12];
  const float* gb2   = (const float*)d_in[13];
  const float* We1   = (const float*)d_in[14];
  const float* be1   = (const float*)d_in[15];
  const float* We2   = (const float*)d_in[16];
  const float* be2   = (const float*)d_in[17];
  const float* tW1   = (const float*)d_in[18];
  const float* tb1   = (const float*)d_in[19];
  const float* tW2   = (const float*)d_in[20];
  const float* tb2   = (const float*)d_in[21];
  const float* tW3   = (const float*)d_in[22];
  const float* tb3   = (const float*)d_in[23];
  const int* taskPtr = (const int*)d_in[24];

  float* out = (float*)d_out;
  char* ws = (char*)d_ws;
  const size_t MB = 1ull << 20;

  // Lifetime-aliased workspace (peak ~209 MB):
  //  [0,64):    feat fp32 -> mix[0,32), t1[32,48), t2[48,56)
  //  [64,192):  h fp32 -> We1t(2lev)[64,96), We2t(2lev)[96,112), e1b[112,160), eob[160,208)
  //  [192,204): W1t(3lev) -> W2t(3lev) -> gbuf[192,200) -> eob tail
  //  [208,~209): metadata
  float* feat = (float*)(ws);
  float* mix  = (float*)(ws);
  float* t1   = (float*)(ws + 32 * MB);
  float* t2v  = (float*)(ws + 48 * MB);
  float* h    = (float*)(ws + 64 * MB);
  unsigned short* We1t0 = (unsigned short*)(ws + 64 * MB);
  unsigned short* We1t1 = (unsigned short*)(ws + 80 * MB);
  unsigned short* We2t0 = (unsigned short*)(ws + 96 * MB);
  unsigned short* We2t1 = (unsigned short*)(ws + 104 * MB);
  unsigned short* e1b   = (unsigned short*)(ws + 112 * MB);
  unsigned short* eob   = (unsigned short*)(ws + 160 * MB);
  unsigned short* Wt0   = (unsigned short*)(ws + 192 * MB);  // W1t then W2t (4MB/level)
  unsigned short* Wt1   = (unsigned short*)(ws + 196 * MB);
  unsigned short* Wt2   = (unsigned short*)(ws + 200 * MB);
  float* gbuf = (float*)(ws + 192 * MB);
  char* small = ws + 208 * MB;
  int*   counts  = (int*)  (small);
  int*   offs    = (int*)  (small + 1024);
  int*   cursor  = (int*)  (small + 2048);
  int*   topkIdx = (int*)  (small + 4096);
  float* topkW   = (float*)(small + 4096 + 196608);
  int*   pairRow = (int*)  (small + 4096 + 2 * 196608);
  float* pairW   = (float*)(small + 4096 + 3 * 196608);
  int*   rowPos  = (int*)  (small + 4096 + 4 * 196608);

  hipMemsetAsync(counts, 0, 64, stream);

  const dim3 blk(256, 1, 1);

  // encoder GEMM1: h = concat(embP,embR) @ W1 + b1  (triple-split, 6 terms)
  transp_k<3><<<dim3(DIN/32, DHID/32, 1), blk, 0, stream>>>(encW1, Wt0, Wt1, Wt2, DIN, DHID);
  mgemm_k<3,3,2,3,0,32><<<dim3(BATCH/128, DHID/128, 1), blk, 0, stream>>>(
      embP, embR, Wt0, Wt1, Wt2, encB1, h, nullptr,
      nullptr, nullptr, nullptr, nullptr, BATCH, DHID, DIN);
  ln_k<DHID, true><<<dim3(BATCH, 1, 1), blk, 0, stream>>>(h, ln1g, ln1b);

  // encoder GEMM2: feat = h @ W2 + b2  (triple-split, 6 terms)
  transp_k<3><<<dim3(DHID/32, DIN/32, 1), blk, 0, stream>>>(encW2, Wt0, Wt1, Wt2, DHID, DIN);
  mgemm_k<3,3,2,0,0,32><<<dim3(BATCH/128, DIN/128, 1), blk, 0, stream>>>(
      h, nullptr, Wt0, Wt1, Wt2, encB2, feat, nullptr,
      nullptr, nullptr, nullptr, nullptr, BATCH, DIN, DHID);
  ln_k<DIN, false><<<dim3(BATCH, 1, 1), blk, 0, stream>>>(feat, ln2g, ln2b);

  // gate (round-1 fp32 path on fp32 feat)
  gemm32_k<true><<<dim3(BATCH/128, 1, 1), blk, 0, stream>>>(
      feat, gW1, gb1, gbuf, taskPtr, BATCH, 128, DIN);
  gate_topk_k<<<dim3(BATCH/4, 1, 1), blk, 0, stream>>>(
      gbuf, gW2, gb2, taskPtr, out + BATCH + 1, topkIdx, topkW, counts);
  scan_k<<<dim3(1, 1, 1), dim3(64, 1, 1), 0, stream>>>(counts, offs, cursor);
  fill_k<<<dim3(BATCH/256, 1, 1), blk, 0, stream>>>(topkIdx, topkW, cursor, pairRow, pairW, rowPos);

  // expert weights, 2-level split (h region free now)
  transp_k<2><<<dim3(DIN/32, EXPSZ/32, NEXP), blk, 0, stream>>>(We1, We1t0, We1t1, nullptr, DIN, EXPSZ);
  transp_k<2><<<dim3(EXPSZ/32, EXPSZ/32, NEXP), blk, 0, stream>>>(We2, We2t0, We2t1, nullptr, EXPSZ, EXPSZ);

  // expert GEMM1: e1 = relu(feat[pairRow] @ We1[e] + be1)  (2x2 split, 3 terms)
  mgemm_k<2,2,1,1,1,64><<<dim3(BATCH/128, EXPSZ/128, NEXP), blk, 0, stream>>>(
      feat, nullptr, We1t0, We1t1, nullptr, be1, nullptr, e1b,
      pairRow, nullptr, counts, offs, NPAIR, EXPSZ, DIN);
  // expert GEMM2: eo = w_p * (e1 @ We2[e] + be2)  (A bf16, B split, 2 terms)
  mgemm_k<1,2,1,2,2,64><<<dim3(BATCH/128, EXPSZ/128, NEXP), blk, 0, stream>>>(
      e1b, nullptr, We2t0, We2t1, nullptr, be2, nullptr, eob,
      nullptr, pairW, counts, offs, NPAIR, EXPSZ, EXPSZ);
  mixreduce_k<<<dim3(BATCH, 1, 1), blk, 0, stream>>>(eob, rowPos, mix);

  // towers (fp32)
  gemm32_k<true><<<dim3(BATCH/128, 2, 1), blk, 0, stream>>>(
      mix, tW1, tb1, t1, taskPtr, BATCH, 256, EXPSZ);
  gemm32_k<true><<<dim3(BATCH/128, 1, 1), blk, 0, stream>>>(
      t1, tW2, tb2, t2v, taskPtr, BATCH, 128, 256);
  tower3_k<<<dim3(BATCH/4, 1, 1), blk, 0, stream>>>(t2v, tW3, tb3, taskPtr, out);
}

// Round 5
// 2019.831 us; speedup vs baseline: 1.9617x; 1.3635x over previous
//
#include <hip/hip_runtime.h>

typedef __attribute__((ext_vector_type(8))) short bf16x8;
typedef __attribute__((ext_vector_type(4))) float f32x4;

#define DEVINL __device__ __forceinline__

constexpr int BATCH = 16384;
constexpr int DIN   = 1024;
constexpr int DHID  = 2048;
constexpr int NEXP  = 16;
constexpr int EXPSZ = 512;
constexpr int NPAIR = BATCH * 3;

DEVINL float bf2f(unsigned short v) {
  union { unsigned u; float f; } x; x.u = ((unsigned)v) << 16; return x.f;
}
DEVINL unsigned short f2bfbits(float f) {   // round-to-nearest-even bf16
  union { float f; unsigned u; } x; x.f = f;
  unsigned r = x.u + 0x7fff + ((x.u >> 16) & 1);
  return (unsigned short)(r >> 16);
}

DEVINL void gl2lds(const unsigned short* src, char* ldst) {
  __builtin_amdgcn_global_load_lds((const __attribute__((address_space(1))) void*)src,
                                   (__attribute__((address_space(3))) void*)ldst, 16, 0, 0);
}

// ---------------------------------------------------------------------------
// Split-bf16 MFMA GEMM, 128x128 tile, 4 waves (2x2 of 64x64), 16x16x32 bf16.
// A source is fp32 (reg-staged, split in-register into ALEV bf16 levels) or
// bf16 (global_load_lds). B pre-split into BLEV bf16 arrays Bt[N][K] (per
// expert when AMODE 1/2). Terms a_i x b_j with i+j <= LMAX are accumulated
// (smallest first). LDS fragment-contiguous: unit u (16B) = g*128 + row,
// holding elems [row][kt + g*8 .. +7].
// AMODE: 0 = linear fp32 rows      (encoder GEMM2)
//        1 = gather fp32 rows via pairRow (expert GEMM1)
//        2 = pair-linear bf16 rows (expert GEMM2)
//        3 = concat(embP,embR) fp32 (encoder GEMM1; Av=embP, Av2=embR)
// EPI:   0 = +bias -> fp32 Cf
//        1 = +bias, relu -> bf16 Cb
//        2 = +bias, *pairW -> bf16 Cb
// ---------------------------------------------------------------------------
template<int ALEV, int BLEV, int LMAX, int AMODE, int EPI, int BK>
__global__ __launch_bounds__(256, 2)
void mgemm_k(const void* __restrict__ Av, const void* __restrict__ Av2,
             const unsigned short* __restrict__ B0p,
             const unsigned short* __restrict__ B1p,
             const unsigned short* __restrict__ B2p,
             const float* __restrict__ biasb,
             float* __restrict__ Cf, unsigned short* __restrict__ Cb,
             const int* __restrict__ pairRow, const float* __restrict__ pairW,
             const int* __restrict__ counts, const int* __restrict__ offs,
             int M, int N, int K)
{
  constexpr int KG = BK / 8;
  constexpr int UNITS = 128 * KG;
  constexpr int ISS = UNITS / 256;
  constexpr bool AFP32 = (AMODE != 2);
  constexpr bool EXPERT = (AMODE == 1 || AMODE == 2);
  __shared__ char smem[(ALEV + BLEV) * UNITS * 16];
  char* sA0 = smem;
  char* sA1 = smem + UNITS * 16;
  char* sA2 = smem + 2 * UNITS * 16;
  char* sB0 = smem + ALEV * UNITS * 16;
  char* sB1 = smem + (ALEV + 1) * UNITS * 16;
  char* sB2 = smem + (ALEV + 2) * UNITS * 16;

  int Mloc = M, rowBase = 0;
  const unsigned short* b0 = B0p;
  const unsigned short* b1 = B1p;
  const unsigned short* b2 = B2p;
  const float* bias = biasb;
  if (EXPERT) {
    const int e = blockIdx.z;
    Mloc = counts[e];
    rowBase = offs[e];
    const size_t eo = (size_t)e * (size_t)K * N;
    b0 = B0p + eo;
    if (BLEV > 1) b1 = B1p + eo;
    if (BLEV > 2) b2 = B2p + eo;
    bias = biasb + (size_t)e * N;
  }
  const int tile0 = blockIdx.x * 128;
  if (tile0 >= Mloc) return;
  const int col0 = blockIdx.y * 128;
  const int tid = threadIdx.x;
  const int lane = tid & 63;
  const int wr = ((tid >> 6) >> 1) * 64;
  const int wc = ((tid >> 6) & 1) * 64;

  // per-thread staging row (fixed across K)
  const int srow = tid & 127;
  const float* aP = nullptr;           // concat halves (AMODE 3)
  const float* aR = nullptr;
  const float* aF = nullptr;           // fp32 row (AMODE 0/1)
  const unsigned short* aB = nullptr;  // bf16 row (AMODE 2)
  if (AMODE == 3) {
    aP = (const float*)Av  + (size_t)(tile0 + srow) * 512;
    aR = (const float*)Av2 + (size_t)(tile0 + srow) * 512;
  } else if (AMODE == 0) {
    aF = (const float*)Av + (size_t)(tile0 + srow) * K;
  } else if (AMODE == 1) {
    int p = rowBase + tile0 + srow; p = p < NPAIR - 1 ? p : NPAIR - 1;
    aF = (const float*)Av + (size_t)pairRow[p] * K;
  } else {
    int p = rowBase + tile0 + srow; p = p < NPAIR - 1 ? p : NPAIR - 1;
    aB = (const unsigned short*)Av + (size_t)p * K;
  }
  const size_t boff = (size_t)(col0 + srow) * K;

  f32x4 acc[4][4];
  #pragma unroll
  for (int m = 0; m < 4; ++m)
    #pragma unroll
    for (int n = 0; n < 4; ++n) acc[m][n] = f32x4{0.f, 0.f, 0.f, 0.f};

  for (int kt = 0; kt < K; kt += BK) {
    if (AFP32) {
      // reg-stage A: load fp32, split to ALEV bf16 levels, ds_write
      #pragma unroll
      for (int it = 0; it < ISS; ++it) {
        const int u = it * 256 + tid;
        const int ko = kt + (u >> 7) * 8;
        const float* s;
        if (AMODE == 3) s = (ko < 512) ? (aP + ko) : (aR + (ko - 512));
        else            s = aF + ko;
        const float4 x0 = *(const float4*)s;
        const float4 x1 = *(const float4*)(s + 4);
        const float vv[8] = {x0.x, x0.y, x0.z, x0.w, x1.x, x1.y, x1.z, x1.w};
        bf16x8 q0, q1, q2;
        #pragma unroll
        for (int j = 0; j < 8; ++j) {
          const unsigned short c0 = f2bfbits(vv[j]);
          q0[j] = (short)c0;
          if (ALEV > 1) {
            const float r1v = vv[j] - bf2f(c0);
            const unsigned short c1 = f2bfbits(r1v);
            q1[j] = (short)c1;
            if (ALEV > 2) q2[j] = (short)f2bfbits(r1v - bf2f(c1));
          }
        }
        *(bf16x8*)(sA0 + (size_t)u * 16) = q0;
        if (ALEV > 1) *(bf16x8*)(sA1 + (size_t)u * 16) = q1;
        if (ALEV > 2) *(bf16x8*)(sA2 + (size_t)u * 16) = q2;
      }
    }
    #pragma unroll
    for (int it = 0; it < ISS; ++it) {
      const int g = it * 2 + (tid >> 7);
      const int uo = (it * 256 + (tid & 192)) * 16;   // wave-uniform LDS base
      const int ko = kt + g * 8;
      if (!AFP32) gl2lds(aB + ko, sA0 + uo);
      gl2lds(b0 + boff + ko, sB0 + uo);
      if (BLEV > 1) gl2lds(b1 + boff + ko, sB1 + uo);
      if (BLEV > 2) gl2lds(b2 + boff + ko, sB2 + uo);
    }
    __syncthreads();
    #pragma unroll
    for (int kk = 0; kk < BK / 32; ++kk) {
      const int g = kk * 4 + (lane >> 4);
      bf16x8 b0f[4], b1f[4], b2f[4];
      #pragma unroll
      for (int n = 0; n < 4; ++n) {
        const size_t off = (size_t)(g * 128 + wc + n * 16 + (lane & 15)) * 16;
        b0f[n] = *(const bf16x8*)(sB0 + off);
        if (BLEV > 1) b1f[n] = *(const bf16x8*)(sB1 + off);
        if (BLEV > 2) b2f[n] = *(const bf16x8*)(sB2 + off);
      }
      #pragma unroll
      for (int m = 0; m < 4; ++m) {
        const size_t aoff = (size_t)(g * 128 + wr + m * 16 + (lane & 15)) * 16;
        const bf16x8 a0 = *(const bf16x8*)(sA0 + aoff);
        bf16x8 a1, a2;
        if (ALEV > 1) a1 = *(const bf16x8*)(sA1 + aoff);
        if (ALEV > 2) a2 = *(const bf16x8*)(sA2 + aoff);
        #pragma unroll
        for (int n = 0; n < 4; ++n) {
          // smallest-magnitude terms first
          if (ALEV > 2 && LMAX >= 2)
            acc[m][n] = __builtin_amdgcn_mfma_f32_16x16x32_bf16(a2, b0f[n], acc[m][n], 0, 0, 0);
          if (ALEV > 1 && BLEV > 1 && LMAX >= 2)
            acc[m][n] = __builtin_amdgcn_mfma_f32_16x16x32_bf16(a1, b1f[n], acc[m][n], 0, 0, 0);
          if (BLEV > 2 && LMAX >= 2)
            acc[m][n] = __builtin_amdgcn_mfma_f32_16x16x32_bf16(a0, b2f[n], acc[m][n], 0, 0, 0);
          if (ALEV > 1 && LMAX >= 1)
            acc[m][n] = __builtin_amdgcn_mfma_f32_16x16x32_bf16(a1, b0f[n], acc[m][n], 0, 0, 0);
          if (BLEV > 1 && LMAX >= 1)
            acc[m][n] = __builtin_amdgcn_mfma_f32_16x16x32_bf16(a0, b1f[n], acc[m][n], 0, 0, 0);
          acc[m][n] = __builtin_amdgcn_mfma_f32_16x16x32_bf16(a0, b0f[n], acc[m][n], 0, 0, 0);
        }
      }
    }
    __syncthreads();
  }

  // epilogue. C/D mapping: col = lane&15, row = (lane>>4)*4 + j  [m89-verified]
  #pragma unroll
  for (int n = 0; n < 4; ++n) {
    const int cn = col0 + wc + n * 16 + (lane & 15);
    const float bv = bias[cn];
    #pragma unroll
    for (int m = 0; m < 4; ++m) {
      const int r0 = wr + m * 16 + ((lane >> 4) << 2);
      #pragma unroll
      for (int j = 0; j < 4; ++j) {
        const int rm = tile0 + r0 + j;
        if (EXPERT && rm >= Mloc) continue;
        const float v = acc[m][n][j] + bv;
        const size_t ci = (size_t)(EXPERT ? (rowBase + rm) : rm) * N + cn;
        if (EPI == 0) {
          Cf[ci] = v;
        } else if (EPI == 1) {
          Cb[ci] = f2bfbits(fmaxf(v, 0.f));
        } else {
          Cb[ci] = f2bfbits(v * pairW[rowBase + rm]);
        }
      }
    }
  }
}

// ---------------------------------------------------------------------------
// fp32 vector GEMM (gate + towers). C = relu(A@B[t] + bias[t]), fp32.
// ---------------------------------------------------------------------------
template<bool RELU>
__global__ __launch_bounds__(256, 2)
void gemm32_k(const float* __restrict__ Av, const float* __restrict__ Bb,
              const float* __restrict__ biasb, float* __restrict__ Cv,
              const int* __restrict__ taskPtr, int M, int N, int K)
{
  __shared__ float As[16][128];
  __shared__ float Bs[16][128];
  const int t = *taskPtr;
  const float* Bw = Bb + (size_t)t * K * N;
  const float* bias = biasb + (size_t)t * N;
  const int tile0 = blockIdx.x * 128;
  const int col0 = blockIdx.y * 128;
  const int tid = threadIdx.x;
  const int am = tid >> 1, ak = (tid & 1) * 8;
  const int bk = tid >> 4, bn = (tid & 15) * 8;
  const int rg = (tid >> 4) * 8, cg = (tid & 15) * 8;
  const float* aptr = Av + (size_t)(tile0 + am) * K;

  float acc[8][8];
  #pragma unroll
  for (int i = 0; i < 8; ++i)
    #pragma unroll
    for (int j = 0; j < 8; ++j) acc[i][j] = 0.f;

  for (int kt = 0; kt < K; kt += 16) {
    {
      const float* src = aptr + kt + ak;
      float4 x0 = *reinterpret_cast<const float4*>(src);
      float4 x1 = *reinterpret_cast<const float4*>(src + 4);
      As[ak+0][am]=x0.x; As[ak+1][am]=x0.y; As[ak+2][am]=x0.z; As[ak+3][am]=x0.w;
      As[ak+4][am]=x1.x; As[ak+5][am]=x1.y; As[ak+6][am]=x1.z; As[ak+7][am]=x1.w;
    }
    {
      const float* bsrc = Bw + (size_t)(kt + bk) * N + (col0 + bn);
      float4 b0 = *reinterpret_cast<const float4*>(bsrc);
      float4 b1 = *reinterpret_cast<const float4*>(bsrc + 4);
      Bs[bk][bn+0]=b0.x; Bs[bk][bn+1]=b0.y; Bs[bk][bn+2]=b0.z; Bs[bk][bn+3]=b0.w;
      Bs[bk][bn+4]=b1.x; Bs[bk][bn+5]=b1.y; Bs[bk][bn+6]=b1.z; Bs[bk][bn+7]=b1.w;
    }
    __syncthreads();
    #pragma unroll
    for (int k = 0; k < 16; ++k) {
      float4 a0 = *reinterpret_cast<const float4*>(&As[k][rg]);
      float4 a1 = *reinterpret_cast<const float4*>(&As[k][rg + 4]);
      float4 c0 = *reinterpret_cast<const float4*>(&Bs[k][cg]);
      float4 c1 = *reinterpret_cast<const float4*>(&Bs[k][cg + 4]);
      const float a[8] = {a0.x,a0.y,a0.z,a0.w,a1.x,a1.y,a1.z,a1.w};
      const float b[8] = {c0.x,c0.y,c0.z,c0.w,c1.x,c1.y,c1.z,c1.w};
      #pragma unroll
      for (int i = 0; i < 8; ++i)
        #pragma unroll
        for (int j = 0; j < 8; ++j)
          acc[i][j] = fmaf(a[i], b[j], acc[i][j]);
    }
    __syncthreads();
  }
  #pragma unroll
  for (int i = 0; i < 8; ++i) {
    const int mr = tile0 + rg + i;
    #pragma unroll
    for (int j = 0; j < 8; ++j) {
      float v = acc[i][j] + bias[col0 + cg + j];
      if (RELU) v = fmaxf(v, 0.f);
      Cv[(size_t)mr * N + col0 + cg + j] = v;
    }
  }
}

// ---------------------------------------------------------------------------
// transpose+convert: src fp32 [z][R][C] -> LEV bf16 split levels, [z][C][R]
// ---------------------------------------------------------------------------
template<int LEV>
__global__ __launch_bounds__(256)
void transp_k(const float* __restrict__ src, unsigned short* __restrict__ d0,
              unsigned short* __restrict__ d1, unsigned short* __restrict__ d2,
              int R, int C)
{
  __shared__ float tle[32][33];
  const size_t bb = (size_t)blockIdx.z * R * C;
  const int r0 = blockIdx.x * 32, c0 = blockIdx.y * 32;
  const int x = threadIdx.x & 31, y = threadIdx.x >> 5;
  #pragma unroll
  for (int i = 0; i < 32; i += 8)
    tle[y + i][x] = src[bb + (size_t)(r0 + y + i) * C + (c0 + x)];
  __syncthreads();
  #pragma unroll
  for (int i = 0; i < 32; i += 8) {
    const float v = tle[x][y + i];
    const size_t di = bb + (size_t)(c0 + y + i) * R + (r0 + x);
    const unsigned short b0 = f2bfbits(v);
    d0[di] = b0;
    if (LEV > 1) {
      const float r1 = v - bf2f(b0);
      const unsigned short b1 = f2bfbits(r1);
      d1[di] = b1;
      if (LEV > 2) d2[di] = f2bfbits(r1 - bf2f(b1));
    }
  }
}

// ---------------------------------------------------------------------------
// In-place LayerNorm (+ optional relu) over fp32 rows of COLS.
// ---------------------------------------------------------------------------
template<int COLS, bool RELU>
__global__ __launch_bounds__(256)
void ln_k(float* __restrict__ x, const float* __restrict__ g, const float* __restrict__ b)
{
  constexpr int PER = COLS / 256;
  const size_t row = blockIdx.x;
  float* xr = x + row * COLS;
  float v[PER];
  float s = 0.f, s2 = 0.f;
  #pragma unroll
  for (int i = 0; i < PER; ++i) {
    v[i] = xr[threadIdx.x + i * 256];
    s += v[i];
    s2 += v[i] * v[i];
  }
  #pragma unroll
  for (int o = 1; o < 64; o <<= 1) { s += __shfl_xor(s, o); s2 += __shfl_xor(s2, o); }
  __shared__ float ss[4], ss2[4];
  const int w = threadIdx.x >> 6;
  if ((threadIdx.x & 63) == 0) { ss[w] = s; ss2[w] = s2; }
  __syncthreads();
  s  = ss[0] + ss[1] + ss[2] + ss[3];
  s2 = ss2[0] + ss2[1] + ss2[2] + ss2[3];
  const float mu = s * (1.f / COLS);
  const float var = s2 * (1.f / COLS) - mu * mu;
  const float rs = rsqrtf(var + 1e-5f);
  #pragma unroll
  for (int i = 0; i < PER; ++i) {
    const int c = threadIdx.x + i * 256;
    float y = (v[i] - mu) * rs * g[c] + b[c];
    if (RELU) y = fmaxf(y, 0.f);
    xr[c] = y;
  }
}

// ---------------------------------------------------------------------------
// gate: logits = relu-g @ gW2[t] + gb2[t]; top-3 softmax; NO global atomics.
// ---------------------------------------------------------------------------
__global__ __launch_bounds__(256)
void gate_topk_k(const float* __restrict__ g, const float* __restrict__ gW2,
                 const float* __restrict__ gb2, const int* __restrict__ taskPtr,
                 float* __restrict__ gatesOut, int* __restrict__ topkIdx,
                 float* __restrict__ topkW)
{
  const int t = *taskPtr;
  const float* W = gW2 + (size_t)t * 128 * 16;
  const float* bias = gb2 + (size_t)t * 16;
  const int lane = threadIdx.x & 63;
  const int row = blockIdx.x * 4 + (threadIdx.x >> 6);
  const float* gr = g + (size_t)row * 128;
  const int e = lane & 15;
  const int q = lane >> 4;
  float s = 0.f;
  for (int j = q * 32; j < q * 32 + 32; ++j) s = fmaf(gr[j], W[j * 16 + e], s);
  s += __shfl_xor(s, 16);
  s += __shfl_xor(s, 32);
  s += bias[e];
  float logits[16];
  #pragma unroll
  for (int i = 0; i < 16; ++i) logits[i] = __shfl(s, i);
  int i0 = 0; float v0 = logits[0];
  #pragma unroll
  for (int i = 1; i < 16; ++i) if (logits[i] > v0) { v0 = logits[i]; i0 = i; }
  int i1 = -1; float v1 = -3.4e38f;
  #pragma unroll
  for (int i = 0; i < 16; ++i) if (i != i0 && logits[i] > v1) { v1 = logits[i]; i1 = i; }
  int i2 = -1; float v2 = -3.4e38f;
  #pragma unroll
  for (int i = 0; i < 16; ++i) if (i != i0 && i != i1 && logits[i] > v2) { v2 = logits[i]; i2 = i; }
  const float ex1 = expf(v1 - v0);
  const float ex2 = expf(v2 - v0);
  const float inv = 1.f / (1.f + ex1 + ex2);
  const float p0 = inv, p1 = ex1 * inv, p2 = ex2 * inv;
  if (lane < 16) {
    const float gv = (lane == i0) ? p0 : (lane == i1) ? p1 : (lane == i2) ? p2 : 0.f;
    gatesOut[(size_t)row * 16 + lane] = gv;
  }
  if (lane == 0) {
    topkIdx[row * 3 + 0] = i0; topkIdx[row * 3 + 1] = i1; topkIdx[row * 3 + 2] = i2;
    topkW [row * 3 + 0] = p0; topkW [row * 3 + 1] = p1; topkW [row * 3 + 2] = p2;
  }
}

// per-chunk expert histogram (LDS atomics only)
__global__ __launch_bounds__(256)
void hist_k(const int* __restrict__ topkIdx, int* __restrict__ chunkCnt)
{
  __shared__ int lc[NEXP];
  if (threadIdx.x < NEXP) lc[threadIdx.x] = 0;
  __syncthreads();
  const int row = blockIdx.x * 256 + threadIdx.x;
  #pragma unroll
  for (int k = 0; k < 3; ++k) atomicAdd(&lc[topkIdx[row * 3 + k]], 1);
  __syncthreads();
  if (threadIdx.x < NEXP) chunkCnt[blockIdx.x * NEXP + threadIdx.x] = lc[threadIdx.x];
}

// serial scan: counts/offs per expert + per-chunk bases (2048 adds, ~µs)
__global__ void scanB_k(const int* __restrict__ chunkCnt, int* __restrict__ counts,
                        int* __restrict__ offs, int* __restrict__ chunkBase)
{
  if (threadIdx.x == 0) {
    int tot[NEXP];
    for (int e = 0; e < NEXP; ++e) tot[e] = 0;
    for (int c = 0; c < 64; ++c)
      for (int e = 0; e < NEXP; ++e) tot[e] += chunkCnt[c * NEXP + e];
    int a = 0;
    for (int e = 0; e < NEXP; ++e) { offs[e] = a; counts[e] = tot[e]; a += tot[e]; }
    for (int e = 0; e < NEXP; ++e) {
      int b = offs[e];
      for (int c = 0; c < 64; ++c) { chunkBase[c * NEXP + e] = b; b += chunkCnt[c * NEXP + e]; }
    }
  }
}

// fill pair lists: LDS-atomic within-chunk offsets + precomputed chunk base
__global__ __launch_bounds__(256)
void fill2_k(const int* __restrict__ topkIdx, const float* __restrict__ topkW,
             const int* __restrict__ chunkBase, int* __restrict__ pairRow,
             float* __restrict__ pairW, int* __restrict__ rowPos)
{
  __shared__ int lc[NEXP];
  if (threadIdx.x < NEXP) lc[threadIdx.x] = 0;
  __syncthreads();
  const int row = blockIdx.x * 256 + threadIdx.x;
  #pragma unroll
  for (int k = 0; k < 3; ++k) {
    const int e = topkIdx[row * 3 + k];
    const int lofs = atomicAdd(&lc[e], 1);
    const int pos = chunkBase[blockIdx.x * NEXP + e] + lofs;
    pairRow[pos] = row;
    pairW[pos] = topkW[row * 3 + k];
    rowPos[row * 3 + k] = pos;
  }
}

__global__ __launch_bounds__(256)
void mixreduce_k(const unsigned short* __restrict__ eo, const int* __restrict__ rowPos,
                 float* __restrict__ mix)
{
  const size_t row = blockIdx.x;
  const size_t p0 = rowPos[row * 3 + 0];
  const size_t p1 = rowPos[row * 3 + 1];
  const size_t p2 = rowPos[row * 3 + 2];
  for (int c = threadIdx.x; c < EXPSZ; c += 256) {
    mix[row * EXPSZ + c] = bf2f(eo[p0 * EXPSZ + c]) + bf2f(eo[p1 * EXPSZ + c])
                         + bf2f(eo[p2 * EXPSZ + c]);
  }
}

__global__ __launch_bounds__(256)
void tower3_k(const float* __restrict__ t2, const float* __restrict__ tW3,
              const float* __restrict__ tb3, const int* __restrict__ taskPtr,
              float* __restrict__ out)
{
  const int t = *taskPtr;
  const float* w = tW3 + (size_t)t * 128;
  const float bias = tb3[t];
  const int lane = threadIdx.x & 63;
  const int row = blockIdx.x * 4 + (threadIdx.x >> 6);
  const float* x = t2 + (size_t)row * 128;
  float s = fmaf(x[lane], w[lane], x[lane + 64] * w[lane + 64]);
  #pragma unroll
  for (int o = 1; o < 64; o <<= 1) s += __shfl_xor(s, o);
  if (lane == 0) out[row] = 1.f / (1.f + expf(-(s + bias)));
  if (blockIdx.x == 0 && threadIdx.x == 0) out[BATCH] = (float)t;
}

// ---------------------------------------------------------------------------
extern "C" void kernel_launch(void* const* d_in, const int* in_sizes, int n_in,
                              void* d_out, int out_size, void* d_ws, size_t ws_size,
                              hipStream_t stream)
{
  (void)in_sizes; (void)n_in; (void)out_size; (void)ws_size;
  const float* embP  = (const float*)d_in[0];
  const float* embR  = (const float*)d_in[1];
  const float* encW1 = (const float*)d_in[2];
  const float* encB1 = (const float*)d_in[3];
  const float* ln1g  = (const float*)d_in[4];
  const float* ln1b  = (const float*)d_in[5];
  const float* encW2 = (const float*)d_in[6];
  const float* encB2 = (const float*)d_in[7];
  const float* ln2g  = (const float*)d_in[8];
  const float* ln2b  = (const float*)d_in[9];
  const float* gW1   = (const float*)d_in[10];
  const float* gb1   = (const float*)d_in[11];
  const float* gW2   = (const float*)d_in[12];
  const float* gb2   = (const float*)d_in[13];
  const float* We1   = (const float*)d_in[14];
  const float* be1   = (const float*)d_in[15];
  const float* We2   = (const float*)d_in[16];
  const float* be2   = (const float*)d_in[17];
  const float* tW1   = (const float*)d_in[18];
  const float* tb1   = (const float*)d_in[19];
  const float* tW2   = (const float*)d_in[20];
  const float* tb2   = (const float*)d_in[21];
  const float* tW3   = (const float*)d_in[22];
  const float* tb3   = (const float*)d_in[23];
  const int* taskPtr = (const int*)d_in[24];

  float* out = (float*)d_out;
  char* ws = (char*)d_ws;
  const size_t MB = 1ull << 20;

  // Lifetime-aliased workspace (peak ~209 MB):
  //  [0,64):    feat fp32 -> mix[0,32), t1[32,48), t2[48,56)
  //  [64,192):  h fp32 -> We1t(2lev)[64,96), We2t(2lev)[96,112), e1b[112,160), eob[160,208)
  //  [192,204): W1t(3lev) -> W2t(3lev) -> gbuf[192,200)
  //  [208,~209): metadata
  float* feat = (float*)(ws);
  float* mix  = (float*)(ws);
  float* t1   = (float*)(ws + 32 * MB);
  float* t2v  = (float*)(ws + 48 * MB);
  float* h    = (float*)(ws + 64 * MB);
  unsigned short* We1t0 = (unsigned short*)(ws + 64 * MB);
  unsigned short* We1t1 = (unsigned short*)(ws + 80 * MB);
  unsigned short* We2t0 = (unsigned short*)(ws + 96 * MB);
  unsigned short* We2t1 = (unsigned short*)(ws + 104 * MB);
  unsigned short* e1b   = (unsigned short*)(ws + 112 * MB);
  unsigned short* eob   = (unsigned short*)(ws + 160 * MB);
  unsigned short* Wt0   = (unsigned short*)(ws + 192 * MB);  // W1t then W2t (4MB/level)
  unsigned short* Wt1   = (unsigned short*)(ws + 196 * MB);
  unsigned short* Wt2   = (unsigned short*)(ws + 200 * MB);
  float* gbuf = (float*)(ws + 192 * MB);
  char* small = ws + 208 * MB;
  int*   counts    = (int*)  (small);
  int*   offs      = (int*)  (small + 1024);
  int*   chunkCnt  = (int*)  (small + 2048);            // 64*16 ints = 4KB
  int*   chunkBase = (int*)  (small + 2048 + 4096);     // 4KB
  int*   topkIdx   = (int*)  (small + 16384);
  float* topkW     = (float*)(small + 16384 + 196608);
  int*   pairRow   = (int*)  (small + 16384 + 2 * 196608);
  float* pairW     = (float*)(small + 16384 + 3 * 196608);
  int*   rowPos    = (int*)  (small + 16384 + 4 * 196608);

  const dim3 blk(256, 1, 1);

  // encoder GEMM1: h = concat(embP,embR) @ W1 + b1  (triple-split, 6 terms)
  transp_k<3><<<dim3(DIN/32, DHID/32, 1), blk, 0, stream>>>(encW1, Wt0, Wt1, Wt2, DIN, DHID);
  mgemm_k<3,3,2,3,0,32><<<dim3(BATCH/128, DHID/128, 1), blk, 0, stream>>>(
      embP, embR, Wt0, Wt1, Wt2, encB1, h, nullptr,
      nullptr, nullptr, nullptr, nullptr, BATCH, DHID, DIN);
  ln_k<DHID, true><<<dim3(BATCH, 1, 1), blk, 0, stream>>>(h, ln1g, ln1b);

  // encoder GEMM2: feat = h @ W2 + b2  (triple-split, 6 terms)
  transp_k<3><<<dim3(DHID/32, DIN/32, 1), blk, 0, stream>>>(encW2, Wt0, Wt1, Wt2, DHID, DIN);
  mgemm_k<3,3,2,0,0,32><<<dim3(BATCH/128, DIN/128, 1), blk, 0, stream>>>(
      h, nullptr, Wt0, Wt1, Wt2, encB2, feat, nullptr,
      nullptr, nullptr, nullptr, nullptr, BATCH, DIN, DHID);
  ln_k<DIN, false><<<dim3(BATCH, 1, 1), blk, 0, stream>>>(feat, ln2g, ln2b);

  // gate (fp32 path on fp32 feat) — no global atomics anywhere
  gemm32_k<true><<<dim3(BATCH/128, 1, 1), blk, 0, stream>>>(
      feat, gW1, gb1, gbuf, taskPtr, BATCH, 128, DIN);
  gate_topk_k<<<dim3(BATCH/4, 1, 1), blk, 0, stream>>>(
      gbuf, gW2, gb2, taskPtr, out + BATCH + 1, topkIdx, topkW);
  hist_k<<<dim3(BATCH/256, 1, 1), blk, 0, stream>>>(topkIdx, chunkCnt);
  scanB_k<<<dim3(1, 1, 1), dim3(64, 1, 1), 0, stream>>>(chunkCnt, counts, offs, chunkBase);
  fill2_k<<<dim3(BATCH/256, 1, 1), blk, 0, stream>>>(topkIdx, topkW, chunkBase,
                                                     pairRow, pairW, rowPos);

  // expert weights, 2-level split (h region free now)
  transp_k<2><<<dim3(DIN/32, EXPSZ/32, NEXP), blk, 0, stream>>>(We1, We1t0, We1t1, nullptr, DIN, EXPSZ);
  transp_k<2><<<dim3(EXPSZ/32, EXPSZ/32, NEXP), blk, 0, stream>>>(We2, We2t0, We2t1, nullptr, EXPSZ, EXPSZ);

  // expert GEMM1: e1 = relu(feat[pairRow] @ We1[e] + be1)  (2x2 split, 3 terms)
  mgemm_k<2,2,1,1,1,64><<<dim3(BATCH/128, EXPSZ/128, NEXP), blk, 0, stream>>>(
      feat, nullptr, We1t0, We1t1, nullptr, be1, nullptr, e1b,
      pairRow, nullptr, counts, offs, NPAIR, EXPSZ, DIN);
  // expert GEMM2: eo = w_p * (e1 @ We2[e] + be2)  (A bf16, B split, 2 terms)
  mgemm_k<1,2,1,2,2,64><<<dim3(BATCH/128, EXPSZ/128, NEXP), blk, 0, stream>>>(
      e1b, nullptr, We2t0, We2t1, nullptr, be2, nullptr, eob,
      nullptr, pairW, counts, offs, NPAIR, EXPSZ, EXPSZ);
  mixreduce_k<<<dim3(BATCH, 1, 1), blk, 0, stream>>>(eob, rowPos, mix);

  // towers (fp32)
  gemm32_k<true><<<dim3(BATCH/128, 2, 1), blk, 0, stream>>>(
      mix, tW1, tb1, t1, taskPtr, BATCH, 256, EXPSZ);
  gemm32_k<true><<<dim3(BATCH/128, 1, 1), blk, 0, stream>>>(
      t1, tW2, tb2, t2v, taskPtr, BATCH, 128, 256);
  tower3_k<<<dim3(BATCH/4, 1, 1), blk, 0, stream>>>(t2v, tW3, tb3, taskPtr, out);
}